// Round 1
// baseline (555.486 us; speedup 1.0000x reference)
//
#include <hip/hip_runtime.h>
#include <math.h>

// Problem constants (match reference setup_inputs)
#define BN     2
#define QN     4096
#define LN     1024
#define HDN    256
#define INNERN 128
#define TOPKN  128
#define PI_F   3.14159265358979323846f

// ---------------------------------------------------------------------------
// Kernel 1: kv = tokens @ kv_W  -> k_full (B,L,128) row-major, v transposed
// (B,128,L). One block per (b,l) row, 256 threads = 256 output columns.
// ---------------------------------------------------------------------------
__global__ __launch_bounds__(256) void kv_kernel(
    const float* __restrict__ tokens, const float* __restrict__ kv_W,
    float* __restrict__ kf, float* __restrict__ vt)
{
    int bl = blockIdx.x;          // b*1024 + l, 0..2047
    int t  = threadIdx.x;         // 0..255
    __shared__ float tok[256];
    tok[t] = tokens[bl * 256 + t];
    __syncthreads();
    float a = 0.f;
    const float* w = kv_W + t;    // column t, row stride 256
    #pragma unroll 8
    for (int h = 0; h < 256; h++) a += tok[h] * w[h * 256];
    if (t < 128) {
        kf[bl * 128 + t] = a;                       // k_full[b][l][t]
    } else {
        int b = bl >> 10, l = bl & 1023;
        vt[(b * 128 + (t - 128)) * LN + l] = a;     // v_t[b][c][l]
    }
}

// ---------------------------------------------------------------------------
// Kernel 2: q (batch-independent). gamma(64) -> x_q(256) -> q(128) per query.
// One block per query p.
// ---------------------------------------------------------------------------
__global__ __launch_bounds__(256) void q_kernel(
    const float* __restrict__ x, const float* __restrict__ query_W,
    const float* __restrict__ query_b, const float* __restrict__ q_W,
    float* __restrict__ qall)
{
    int p = blockIdx.x;
    int t = threadIdx.x;
    __shared__ float gam[64];
    __shared__ float xq[256];
    if (t < 64) {
        int c = t >> 4, j = t & 15;
        int oi = j & 7;
        float om = (float)(10.0 * pow(12.8, (double)oi / 7.0)); // logspace(1, log10(128), 8)
        float arg = PI_F * x[p * 4 + c] * om;
        gam[t] = (j < 8) ? sinf(arg) : cosf(arg);
    }
    __syncthreads();
    float a = query_b[t];
    #pragma unroll 8
    for (int f = 0; f < 64; f++) a += gam[f] * query_W[f * 256 + t];
    xq[t] = fmaxf(a, 0.f);
    __syncthreads();
    if (t < 128) {
        float qa = 0.f;
        #pragma unroll 8
        for (int i = 0; i < 256; i++) qa += xq[i] * q_W[i * 128 + t];
        qall[p * 128 + t] = qa;
    }
}

// ---------------------------------------------------------------------------
// Kernel 3: fused attention (windowed top-k) + modulation + 2-layer band/mod
// MLP + hv + scalar output. One block per (b,p), 256 threads.
// ---------------------------------------------------------------------------
__global__ __launch_bounds__(256) void attn_mlp_kernel(
    const float* __restrict__ x,
    const float* __restrict__ kf, const float* __restrict__ vt,
    const float* __restrict__ qall,
    const float* __restrict__ out_W, const float* __restrict__ out_b,
    const float* __restrict__ band_W, const float* __restrict__ band_b,
    const float* __restrict__ mod_W, const float* __restrict__ mod_b,
    const float* __restrict__ hv_W, const float* __restrict__ hv_b,
    const float* __restrict__ outl_W, const float* __restrict__ outl_b,
    const int* __restrict__ gDp, const int* __restrict__ gHp,
    const int* __restrict__ gWp, const int* __restrict__ gTp,
    float* __restrict__ out)
{
    int bid = blockIdx.x;
    int b = bid >> 12;            // /4096
    int p = bid & (QN - 1);
    int t = threadIdx.x;

    __shared__ float q_s[128];
    __shared__ float red[256];
    __shared__ float attn_s[256];
    __shared__ float o_s[128];
    __shared__ float modu[256];
    __shared__ float gam[128];    // gam[l*64+f], 2 layers
    __shared__ float m0s[256];
    __shared__ float s01[256];

    // ---- attention window start (exact fp32; see top_k contiguity proof) ----
    int gD = gDp[0], gH = gHp[0], gW = gWp[0], gT = gTp[0];
    float g0 = x[p * 4 + 0], g1 = x[p * 4 + 1];
    float g2 = x[p * 4 + 2], g3 = x[p * 4 + 3];
    int zi = (int)(g0 * (float)gD);
    int yi = (int)(g1 * (float)gH);
    int xi = (int)(g2 * (float)gW);
    int ti = (int)(g3 * (float)gT);
    int idx = ((ti * gD + zi) * gH + yi) * gW + xi;
    int Ng = gD * gH * gW * gT;
    float tt = (float)idx / (float)Ng;
    // window start: s = ceil(t*L - (TOPK/2 + 0.5)); ties resolved like top_k
    int s = (int)ceilf(tt * (float)LN - ((float)(TOPKN / 2) + 0.5f));
    s = min(max(s, 0), LN - TOPKN);

    if (t < 128) q_s[t] = qall[p * 128 + t];
    __syncthreads();

    // ---- sim: thread = (head h = t>>7, key kk = t&127), 64-dim dot ----
    int h = t >> 7;
    int kk = t & 127;
    const float* krow = kf + (size_t)(b * LN + s + kk) * INNERN + h * 64;
    float acc = 0.f;
    #pragma unroll 8
    for (int d = 0; d < 64; d++) acc += q_s[h * 64 + d] * krow[d];
    acc *= 0.125f; // DH^-0.5

    // ---- per-head softmax over 128 keys (heads = block halves) ----
    red[t] = acc;
    __syncthreads();
    for (int st = 64; st > 0; st >>= 1) {
        if ((t & 127) < st) red[t] = fmaxf(red[t], red[t + st]);
        __syncthreads();
    }
    float mx = red[t & 128];
    __syncthreads();
    float e = expf(acc - mx);
    red[t] = e;
    __syncthreads();
    for (int st = 64; st > 0; st >>= 1) {
        if ((t & 127) < st) red[t] += red[t + st];
        __syncthreads();
    }
    float inv = 1.f / red[t & 128];
    __syncthreads();
    attn_s[t] = e * inv;
    __syncthreads();

    // ---- o = attn @ v : thread j<128 computes o[j], v transposed rows ----
    if (t < 128) {
        int hh = t >> 6;
        const float* vrow = vt + (size_t)(b * 128 + t) * LN + s;
        float oacc = 0.f;
        #pragma unroll 8
        for (int k2 = 0; k2 < 128; k2++) oacc += attn_s[hh * 128 + k2] * vrow[k2];
        o_s[t] = oacc;
    }
    __syncthreads();

    // ---- modulation = o @ out_W + out_b ----
    float macc = out_b[t];
    {
        const float* w = out_W + t;
        #pragma unroll 8
        for (int j = 0; j < 128; j++) macc += o_s[j] * w[j * 256];
    }
    modu[t] = macc;

    // ---- layer gammas (OMEGAS_L: scales 128 and 32) ----
    if (t < 128) {
        int l = t >> 6, f = t & 63;
        int c = f >> 4, j = f & 15;
        int oi = j & 7;
        double base = (l == 0) ? 12.8 : 3.2;
        float om = (float)(10.0 * pow(base, (double)oi / 7.0));
        float gc = (c == 0) ? g0 : (c == 1) ? g1 : (c == 2) ? g2 : g3;
        float arg = PI_F * gc * om;
        gam[t] = (j < 8) ? sinf(arg) : cosf(arg);
    }
    __syncthreads();

    // ---- m_l = relu(relu(gamma_l@band_W + band_b) + modu@mod_W + mod_b) ----
    float mv0 = 0.f, mv1 = 0.f;
    #pragma unroll
    for (int l = 0; l < 2; l++) {
        float a = band_b[l * 256 + t];
        const float* bw = band_W + l * (64 * 256) + t;
        #pragma unroll 8
        for (int f = 0; f < 64; f++) a += gam[l * 64 + f] * bw[f * 256];
        a = fmaxf(a, 0.f);
        float m2 = a + mod_b[l * 256 + t];
        const float* mw = mod_W + l * (256 * 256) + t;
        #pragma unroll 8
        for (int c2 = 0; c2 < 256; c2++) m2 += modu[c2] * mw[c2 * 256];
        m2 = fmaxf(m2, 0.f);
        if (l == 0) mv0 = m2; else mv1 = m2;
    }
    m0s[t] = mv0;
    s01[t] = mv0 + mv1;
    __syncthreads();

    // ---- h_v1 = relu((m0 + m1) @ hv_W + hv_b) ----
    float hv = hv_b[t];
    {
        const float* w = hv_W + t;
        #pragma unroll 8
        for (int c2 = 0; c2 < 256; c2++) hv += s01[c2] * w[c2 * 256];
    }
    hv = fmaxf(hv, 0.f);

    // ---- out = m0 @ outl_W[0] + hv1 @ outl_W[1] + biases ----
    float part = m0s[t] * outl_W[t] + hv * outl_W[256 + t];
    red[t] = part;
    __syncthreads();
    for (int st = 128; st > 0; st >>= 1) {
        if (t < st) red[t] += red[t + st];
        __syncthreads();
    }
    if (t == 0) out[b * QN + p] = red[0] + outl_b[0] + outl_b[1];
}

// ---------------------------------------------------------------------------
extern "C" void kernel_launch(void* const* d_in, const int* in_sizes, int n_in,
                              void* d_out, int out_size, void* d_ws, size_t ws_size,
                              hipStream_t stream)
{
    const float* x       = (const float*)d_in[0];
    const float* tokens  = (const float*)d_in[1];
    const float* query_W = (const float*)d_in[2];
    const float* query_b = (const float*)d_in[3];
    const float* q_W     = (const float*)d_in[4];
    const float* kv_W    = (const float*)d_in[5];
    const float* out_W   = (const float*)d_in[6];
    const float* out_b   = (const float*)d_in[7];
    const float* band_W  = (const float*)d_in[8];
    const float* band_b  = (const float*)d_in[9];
    const float* mod_W   = (const float*)d_in[10];
    const float* mod_b   = (const float*)d_in[11];
    const float* hv_W    = (const float*)d_in[12];
    const float* hv_b    = (const float*)d_in[13];
    const float* outl_W  = (const float*)d_in[14];
    const float* outl_b  = (const float*)d_in[15];
    const int*   gD      = (const int*)d_in[16];
    const int*   gH      = (const int*)d_in[17];
    const int*   gW      = (const int*)d_in[18];
    const int*   gT      = (const int*)d_in[19];

    float* ws   = (float*)d_ws;
    float* kf   = ws;                          // 2*1024*128 floats
    float* vt   = ws + 2 * 1024 * 128;         // 2*128*1024 floats
    float* qall = ws + 2 * 2 * 1024 * 128;     // 4096*128 floats
    float* out  = (float*)d_out;

    kv_kernel<<<BN * LN, 256, 0, stream>>>(tokens, kv_W, kf, vt);
    q_kernel<<<QN, 256, 0, stream>>>(x, query_W, query_b, q_W, qall);
    attn_mlp_kernel<<<BN * QN, 256, 0, stream>>>(x, kf, vt, qall,
        out_W, out_b, band_W, band_b, mod_W, mod_b, hv_W, hv_b,
        outl_W, outl_b, gD, gH, gW, gT, out);
}

// Round 2
// 283.175 us; speedup vs baseline: 1.9616x; 1.9616x over previous
//
#include <hip/hip_runtime.h>
#include <math.h>

// Problem constants (match reference setup_inputs)
#define BN     2
#define QN     4096
#define LN     1024
#define TOPKN  128
#define PI_F   3.14159265358979323846f

// ln(12.8)/7 and ln(3.2)/7 — omegas = 10*exp(i*K), matches jnp.logspace to ~1e-7 rel
#define K_OM0  0.3642064529893673
#define K_OM1  0.1661644014008115

// ---------------------------------------------------------------------------
// Kernel 1: kv = tokens @ kv_W -> kvf[b][l][256] (cols 0..127 = K, 128..255 = V)
// 4 token rows per block; weight load reused 4x.
// ---------------------------------------------------------------------------
__global__ __launch_bounds__(256) void kv_kernel(
    const float* __restrict__ tokens, const float* __restrict__ kv_W,
    float* __restrict__ kvf)
{
    int bl0 = blockIdx.x * 4;     // 512 blocks over 2048 rows
    int t   = threadIdx.x;
    __shared__ float tokT[256 * 4];   // [h][r]
    #pragma unroll
    for (int r = 0; r < 4; r++) tokT[t * 4 + r] = tokens[(bl0 + r) * 256 + t];
    __syncthreads();
    float a0 = 0.f, a1 = 0.f, a2 = 0.f, a3 = 0.f;
    const float* w = kv_W + t;
    #pragma unroll 8
    for (int h = 0; h < 256; h++) {
        float wv = w[h * 256];
        float4 tv = *(const float4*)&tokT[h * 4];
        a0 += tv.x * wv; a1 += tv.y * wv; a2 += tv.z * wv; a3 += tv.w * wv;
    }
    kvf[(bl0 + 0) * 256 + t] = a0;
    kvf[(bl0 + 1) * 256 + t] = a1;
    kvf[(bl0 + 2) * 256 + t] = a2;
    kvf[(bl0 + 3) * 256 + t] = a3;
}

// ---------------------------------------------------------------------------
// Kernel 2: q (batch-independent). 4 queries per block.
// gamma(64) -> x_q(256) -> q(128) per query.
// ---------------------------------------------------------------------------
__global__ __launch_bounds__(256) void q_kernel(
    const float* __restrict__ x, const float* __restrict__ query_W,
    const float* __restrict__ query_b, const float* __restrict__ q_W,
    float* __restrict__ qall)
{
    int p0 = blockIdx.x * 4;      // 1024 blocks
    int t  = threadIdx.x;
    __shared__ float gamT[64 * 4];    // [f][r]
    __shared__ float xqT[256 * 4];    // [i][r]
    __shared__ float redq[256 * 4];

    {   // one gamma element per thread: t = f*4 + r
        int f = t >> 2, r = t & 3;
        int c = f >> 4, j = f & 15, oi = j & 7;
        float om = (float)(10.0 * exp((double)oi * K_OM0));
        float arg = PI_F * x[(p0 + r) * 4 + c] * om;
        gamT[t] = (j < 8) ? sinf(arg) : cosf(arg);
    }
    __syncthreads();
    float qb = query_b[t];
    float a0 = qb, a1 = qb, a2 = qb, a3 = qb;
    #pragma unroll 8
    for (int f = 0; f < 64; f++) {
        float wv = query_W[f * 256 + t];
        float4 g4 = *(const float4*)&gamT[f * 4];
        a0 += g4.x * wv; a1 += g4.y * wv; a2 += g4.z * wv; a3 += g4.w * wv;
    }
    float4 xq4 = make_float4(fmaxf(a0, 0.f), fmaxf(a1, 0.f), fmaxf(a2, 0.f), fmaxf(a3, 0.f));
    *(float4*)&xqT[t * 4] = xq4;
    __syncthreads();
    // q = xq @ q_W : split 256 input rows across 2 thread-halves
    int th = t & 127, half = t >> 7;
    float c0 = 0.f, c1 = 0.f, c2 = 0.f, c3 = 0.f;
    const float* w = q_W + th;
    #pragma unroll 8
    for (int i = half * 128; i < half * 128 + 128; i++) {
        float wv = w[i * 128];
        float4 xv = *(const float4*)&xqT[i * 4];
        c0 += xv.x * wv; c1 += xv.y * wv; c2 += xv.z * wv; c3 += xv.w * wv;
    }
    *(float4*)&redq[t * 4] = make_float4(c0, c1, c2, c3);
    __syncthreads();
    if (t < 128) {
        #pragma unroll
        for (int r = 0; r < 4; r++)
            qall[(p0 + r) * 128 + t] = redq[t * 4 + r] + redq[(t + 128) * 4 + r];
    }
}

// ---------------------------------------------------------------------------
// Kernel 3: fused attention + MLP for G=8 queries per block (1024 blocks).
// Every weight load is reused 8x against LDS-staged transposed activations.
// ---------------------------------------------------------------------------
__global__ __launch_bounds__(256, 4) void attn_mlp_kernel(
    const float* __restrict__ x,
    const float* __restrict__ kvf, const float* __restrict__ qall,
    const float* __restrict__ out_W, const float* __restrict__ out_b,
    const float* __restrict__ band_W, const float* __restrict__ band_b,
    const float* __restrict__ mod_W, const float* __restrict__ mod_b,
    const float* __restrict__ hv_W, const float* __restrict__ hv_b,
    const float* __restrict__ outl_W, const float* __restrict__ outl_b,
    const int* __restrict__ gDp, const int* __restrict__ gHp,
    const int* __restrict__ gWp, const int* __restrict__ gTp,
    float* __restrict__ out)
{
    const int bid = blockIdx.x;
    const int b   = bid >> 9;               // 512 blocks per batch
    const int q0  = (bid & 511) * 8;
    const int t   = threadIdx.x;
    const int wid = t >> 6;
    const int lane = t & 63;

    __shared__ float q_s[1024];            // [g][128]
    __shared__ float gamT[2 * 64 * 8];     // [l][f][g]
    __shared__ float o_T[128 * 8];         // [j][g]
    __shared__ float modu_T[256 * 8];      // [c][g]
    __shared__ float s01_T[256 * 8];       // [c][g]
    __shared__ float attn_s[256];
    __shared__ float red[256];
    __shared__ float sh_xc[8][4];
    __shared__ int   sh_s[8];
    __shared__ float wmx[4], wsm[4];
    __shared__ float ored[4 * 8];

    // stage q rows (contiguous) and grid coords
    #pragma unroll
    for (int r = 0; r < 4; r++) q_s[t + 256 * r] = qall[q0 * 128 + t + 256 * r];
    if (t < 32) sh_xc[t >> 2][t & 3] = x[(q0 + (t >> 2)) * 4 + (t & 3)];
    __syncthreads();

    // layer gammas: idx = l*512 + f*8 + g
    #pragma unroll
    for (int r = 0; r < 4; r++) {
        int idx = t + 256 * r;
        int l = idx >> 9, f = (idx >> 3) & 63, g = idx & 7;
        int c = f >> 4, j = f & 15, oi = j & 7;
        float om = (float)(10.0 * exp((double)oi * (l ? K_OM1 : K_OM0)));
        float arg = PI_F * sh_xc[g][c] * om;
        gamT[idx] = (j < 8) ? sinf(arg) : cosf(arg);
    }
    // window starts (same formula as round 1, verified)
    if (t < 8) {
        int gD = gDp[0], gH = gHp[0], gW = gWp[0], gT = gTp[0];
        float g0 = sh_xc[t][0], g1 = sh_xc[t][1], g2 = sh_xc[t][2], g3 = sh_xc[t][3];
        int zi = (int)(g0 * (float)gD);
        int yi = (int)(g1 * (float)gH);
        int xi = (int)(g2 * (float)gW);
        int ti = (int)(g3 * (float)gT);
        int idx = ((ti * gD + zi) * gH + yi) * gW + xi;
        int Ng = gD * gH * gW * gT;
        float tt = (float)idx / (float)Ng;
        int s = (int)ceilf(tt * (float)LN - ((float)(TOPKN / 2) + 0.5f));
        sh_s[t] = min(max(s, 0), LN - TOPKN);
    }
    __syncthreads();

    // ---------------- attention, one query at a time ----------------
    const int h  = t >> 7;       // head (sim phase) / key-half (o phase)
    const int kk = t & 127;      // key (sim phase) / output col (o phase)
    for (int g = 0; g < 8; g++) {
        int s = sh_s[g];
        // sim: 64-dim dot, vectorized K loads (aligned: offset h*64 within 256-f rows)
        const float* krow = kvf + (size_t)(b * LN + s + kk) * 256 + h * 64;
        const float* qrow = q_s + g * 128 + h * 64;
        float ac0 = 0.f, ac1 = 0.f, ac2 = 0.f, ac3 = 0.f;
        #pragma unroll
        for (int d4 = 0; d4 < 16; d4 += 4) {
            float4 k0 = *(const float4*)(krow + d4 * 4);
            float4 k1 = *(const float4*)(krow + d4 * 4 + 4);
            float4 k2 = *(const float4*)(krow + d4 * 4 + 8);
            float4 k3 = *(const float4*)(krow + d4 * 4 + 12);
            ac0 += qrow[d4*4+0]*k0.x + qrow[d4*4+1]*k0.y + qrow[d4*4+2]*k0.z + qrow[d4*4+3]*k0.w;
            ac1 += qrow[d4*4+4]*k1.x + qrow[d4*4+5]*k1.y + qrow[d4*4+6]*k1.z + qrow[d4*4+7]*k1.w;
            ac2 += qrow[d4*4+8]*k2.x + qrow[d4*4+9]*k2.y + qrow[d4*4+10]*k2.z + qrow[d4*4+11]*k2.w;
            ac3 += qrow[d4*4+12]*k3.x + qrow[d4*4+13]*k3.y + qrow[d4*4+14]*k3.z + qrow[d4*4+15]*k3.w;
        }
        float acc = ((ac0 + ac1) + (ac2 + ac3)) * 0.125f;

        // softmax over 128 keys per head: wave shuffle + 2-wave combine
        float m = acc;
        #pragma unroll
        for (int off = 1; off < 64; off <<= 1) m = fmaxf(m, __shfl_xor(m, off));
        if (lane == 0) wmx[wid] = m;
        __syncthreads();
        float mx = fmaxf(wmx[h * 2], wmx[h * 2 + 1]);
        float e = expf(acc - mx);
        float ss = e;
        #pragma unroll
        for (int off = 1; off < 64; off <<= 1) ss += __shfl_xor(ss, off);
        if (lane == 0) wsm[wid] = ss;
        __syncthreads();
        float inv = 1.f / (wsm[h * 2] + wsm[h * 2 + 1]);
        attn_s[t] = e * inv;
        __syncthreads();

        // o = attn @ V: col j = kk, key-half h; per-wave uniform attn broadcast
        int hh = kk >> 6;  // head owning col j (wave-uniform)
        const float* vcol = kvf + (size_t)(b * LN + s + h * 64) * 256 + 128 + kk;
        const float* arow = attn_s + hh * 128 + h * 64;
        float oa0 = 0.f, oa1 = 0.f;
        #pragma unroll 8
        for (int k2 = 0; k2 < 64; k2 += 2) {
            oa0 += arow[k2]     * vcol[k2 * 256];
            oa1 += arow[k2 + 1] * vcol[(k2 + 1) * 256];
        }
        red[t] = oa0 + oa1;
        __syncthreads();
        if (t < 128) o_T[t * 8 + g] = red[t] + red[t + 128];
        __syncthreads();
    }

    // ---------------- modulation = o @ out_W + out_b ----------------
    float acc8[8];
    {
        float ob = out_b[t];
        #pragma unroll
        for (int g = 0; g < 8; g++) acc8[g] = ob;
        #pragma unroll 4
        for (int j = 0; j < 128; j++) {
            float wv = out_W[j * 256 + t];
            float4 o0 = *(const float4*)&o_T[j * 8];
            float4 o1 = *(const float4*)&o_T[j * 8 + 4];
            acc8[0] += o0.x * wv; acc8[1] += o0.y * wv; acc8[2] += o0.z * wv; acc8[3] += o0.w * wv;
            acc8[4] += o1.x * wv; acc8[5] += o1.y * wv; acc8[6] += o1.z * wv; acc8[7] += o1.w * wv;
        }
        *(float4*)&modu_T[t * 8]     = make_float4(acc8[0], acc8[1], acc8[2], acc8[3]);
        *(float4*)&modu_T[t * 8 + 4] = make_float4(acc8[4], acc8[5], acc8[6], acc8[7]);
    }
    __syncthreads();

    // ---------------- band + mod layers ----------------
    float mv0[8];
    #pragma unroll
    for (int l = 0; l < 2; l++) {
        float bb = band_b[l * 256 + t];
        #pragma unroll
        for (int g = 0; g < 8; g++) acc8[g] = bb;
        #pragma unroll 4
        for (int f = 0; f < 64; f++) {
            float wv = band_W[(l * 64 + f) * 256 + t];
            float4 g0 = *(const float4*)&gamT[(l * 64 + f) * 8];
            float4 g1 = *(const float4*)&gamT[(l * 64 + f) * 8 + 4];
            acc8[0] += g0.x * wv; acc8[1] += g0.y * wv; acc8[2] += g0.z * wv; acc8[3] += g0.w * wv;
            acc8[4] += g1.x * wv; acc8[5] += g1.y * wv; acc8[6] += g1.z * wv; acc8[7] += g1.w * wv;
        }
        float mb = mod_b[l * 256 + t];
        #pragma unroll
        for (int g = 0; g < 8; g++) acc8[g] = fmaxf(acc8[g], 0.f) + mb;
        #pragma unroll 4
        for (int c = 0; c < 256; c++) {
            float wv = mod_W[(l * 256 + c) * 256 + t];
            float4 m0 = *(const float4*)&modu_T[c * 8];
            float4 m1 = *(const float4*)&modu_T[c * 8 + 4];
            acc8[0] += m0.x * wv; acc8[1] += m0.y * wv; acc8[2] += m0.z * wv; acc8[3] += m0.w * wv;
            acc8[4] += m1.x * wv; acc8[5] += m1.y * wv; acc8[6] += m1.z * wv; acc8[7] += m1.w * wv;
        }
        if (l == 0) {
            #pragma unroll
            for (int g = 0; g < 8; g++) mv0[g] = fmaxf(acc8[g], 0.f);
        } else {
            float s01[8];
            #pragma unroll
            for (int g = 0; g < 8; g++) s01[g] = mv0[g] + fmaxf(acc8[g], 0.f);
            *(float4*)&s01_T[t * 8]     = make_float4(s01[0], s01[1], s01[2], s01[3]);
            *(float4*)&s01_T[t * 8 + 4] = make_float4(s01[4], s01[5], s01[6], s01[7]);
        }
    }
    __syncthreads();

    // ---------------- h_v1 = relu(s01 @ hv_W + hv_b) ----------------
    {
        float hb = hv_b[t];
        #pragma unroll
        for (int g = 0; g < 8; g++) acc8[g] = hb;
        #pragma unroll 4
        for (int c = 0; c < 256; c++) {
            float wv = hv_W[c * 256 + t];
            float4 s0 = *(const float4*)&s01_T[c * 8];
            float4 s1 = *(const float4*)&s01_T[c * 8 + 4];
            acc8[0] += s0.x * wv; acc8[1] += s0.y * wv; acc8[2] += s0.z * wv; acc8[3] += s0.w * wv;
            acc8[4] += s1.x * wv; acc8[5] += s1.y * wv; acc8[6] += s1.z * wv; acc8[7] += s1.w * wv;
        }
    }

    // ---------------- final scalar head + reduction ----------------
    {
        float w0 = outl_W[t], w1 = outl_W[256 + t];
        float p8[8];
        #pragma unroll
        for (int g = 0; g < 8; g++) {
            float p = mv0[g] * w0 + fmaxf(acc8[g], 0.f) * w1;
            #pragma unroll
            for (int off = 1; off < 64; off <<= 1) p += __shfl_xor(p, off);
            p8[g] = p;
        }
        if (lane == 0) {
            #pragma unroll
            for (int g = 0; g < 8; g++) ored[wid * 8 + g] = p8[g];
        }
        __syncthreads();
        if (t < 8) {
            float s = ored[t] + ored[8 + t] + ored[16 + t] + ored[24 + t]
                    + outl_b[0] + outl_b[1];
            out[b * QN + q0 + t] = s;
        }
    }
}

// ---------------------------------------------------------------------------
extern "C" void kernel_launch(void* const* d_in, const int* in_sizes, int n_in,
                              void* d_out, int out_size, void* d_ws, size_t ws_size,
                              hipStream_t stream)
{
    const float* x       = (const float*)d_in[0];
    const float* tokens  = (const float*)d_in[1];
    const float* query_W = (const float*)d_in[2];
    const float* query_b = (const float*)d_in[3];
    const float* q_W     = (const float*)d_in[4];
    const float* kv_W    = (const float*)d_in[5];
    const float* out_W   = (const float*)d_in[6];
    const float* out_b   = (const float*)d_in[7];
    const float* band_W  = (const float*)d_in[8];
    const float* band_b  = (const float*)d_in[9];
    const float* mod_W   = (const float*)d_in[10];
    const float* mod_b   = (const float*)d_in[11];
    const float* hv_W    = (const float*)d_in[12];
    const float* hv_b    = (const float*)d_in[13];
    const float* outl_W  = (const float*)d_in[14];
    const float* outl_b  = (const float*)d_in[15];
    const int*   gD      = (const int*)d_in[16];
    const int*   gH      = (const int*)d_in[17];
    const int*   gW      = (const int*)d_in[18];
    const int*   gT      = (const int*)d_in[19];

    float* ws   = (float*)d_ws;
    float* kvf  = ws;                          // 2*1024*256 = 524288 floats
    float* qall = ws + BN * LN * 256;          // 4096*128  = 524288 floats
    float* out  = (float*)d_out;

    kv_kernel<<<BN * LN / 4, 256, 0, stream>>>(tokens, kv_W, kvf);
    q_kernel<<<QN / 4, 256, 0, stream>>>(x, query_W, query_b, q_W, qall);
    attn_mlp_kernel<<<BN * QN / 8, 256, 0, stream>>>(x, kvf, qall,
        out_W, out_b, band_W, band_b, mod_W, mod_b, hv_W, hv_b,
        outl_W, outl_b, gD, gH, gW, gT, out);
}